// Round 9
// baseline (669.144 us; speedup 1.0000x reference)
//
#include <hip/hip_runtime.h>

#define NV 200000
#define NDN 25000
#define EPSV 1e-5f

typedef short bf16x8 __attribute__((ext_vector_type(8)));
typedef float f32x16 __attribute__((ext_vector_type(16)));

static __device__ __forceinline__ float silu_f(float v) { return v / (1.0f + __expf(-v)); }
static __device__ __forceinline__ unsigned short f2b(float f) {
    unsigned u = __float_as_uint(f);
    return (unsigned short)((u + 0x7FFFu + ((u >> 16) & 1u)) >> 16);
}
static __device__ __forceinline__ float b2f(unsigned short h) {
    return __uint_as_float(((unsigned)h) << 16);
}
static __device__ __forceinline__ bf16x8 bc8(uint4 v) { return __builtin_bit_cast(bf16x8, v); }
#define MFMA32(a, b, c) __builtin_amdgcn_mfma_f32_32x32x16_bf16(a, b, c, 0, 0, 0)

// async global->LDS, 16B per lane; dest = wave-uniform base + lane*16
static __device__ __forceinline__ void gload_lds16(const uint4* g, uint4* l) {
    __builtin_amdgcn_global_load_lds((const __attribute__((address_space(1))) unsigned*)(g),
                                     (__attribute__((address_space(3))) unsigned*)(l), 16, 0, 0);
}

// workspace byte offsets
#define OFF_STATS1 0                               // 128 f32 (sum[64], sumsq[64])
#define OFF_STATS2 512                             // 256 f32
#define OFF_TP     4096                            // 16*256 f32
#define OFF_W1B    32768                           // bf16 swizzled 27*64*128
#define OFF_W2B    (OFF_W1B + 27 * 64 * 128 * 2)   // 27*128*128
#define OFF_WDB    (OFF_W2B + 27 * 128 * 128 * 2)  // 8*128*128
#define OFF_WIDB   (OFF_WDB + 8 * 128 * 128 * 2)   // 64*128
#define OFF_H1     (2u << 20)                      // bf16 NV*64
#define OFF_H2     (28u << 20)                     // bf16 NV*128 (h2 then h3 in place)
#define OFF_H4     (80u << 20)                     // bf16 NV*128

// ---------------- fused preprocessing kernel ----------------
// blocks [0,108): swz W1 | [108,324): swz W2 | [324,388): swz Wd | [388,392): swz Wid
// blocks [392,408): tp   | [408,808): stats1 (fixed stride 400)

static __device__ __forceinline__ void swz_role(const float* __restrict__ W, uint4* __restrict__ dst,
                                                int Kc, int S, int blk) {
    int t = blk * 256 + threadIdx.x;
    int total = Kc * S * 4 * 64;
    if (t >= total) return;
    int L = t & 63;
    int u = t >> 6;
    int nt = u & 3; u >>= 2;
    int s = u % S;
    int kk = u / S;
    int CI = S * 16;
    int c0 = s * 16 + (L >> 5) * 8;
    int f = nt * 32 + (L & 31);
    union { unsigned short e[8]; uint4 v; } uu;
#pragma unroll
    for (int j = 0; j < 8; j++) uu.e[j] = f2b(W[(kk * CI + c0 + j) * 128 + f]);
    dst[t] = uu.v;
}

__global__ __launch_bounds__(256) void k_pre(const float* __restrict__ x,
                                             const float* __restrict__ t,
                                             const float* __restrict__ Wt,
                                             const float* __restrict__ bt,
                                             const float* __restrict__ W1,
                                             const float* __restrict__ W2,
                                             const float* __restrict__ Wd,
                                             const float* __restrict__ Wid,
                                             float* __restrict__ stats,
                                             float* __restrict__ tp,
                                             uint4* __restrict__ W1b,
                                             uint4* __restrict__ W2b,
                                             uint4* __restrict__ Wdb,
                                             uint4* __restrict__ Widb) {
    __shared__ float shA[256], shB[256];
    int b = blockIdx.x;
    if (b < 108) {
        swz_role(W1, W1b, 27, 4, b);
    } else if (b < 324) {
        swz_role(W2, W2b, 27, 8, b - 108);
    } else if (b < 388) {
        swz_role(Wd, Wdb, 8, 8, b - 324);
    } else if (b < 392) {
        swz_role(Wid, Widb, 1, 4, b - 388);
    } else if (b < 408) {
        int bb = b - 392, o = threadIdx.x;
        shA[o] = silu_f(t[bb * 256 + o]);
        __syncthreads();
        float acc = bt[o];
        for (int e = 0; e < 256; e++) acc += shA[e] * Wt[e * 256 + o];
        tp[bb * 256 + o] = acc;
    } else {
        int bb = b - 408;                        // 400 stats1 blocks, FIXED stride
        int c = threadIdx.x & 63;
        int r0 = bb * 4 + (threadIdx.x >> 6);
        float s = 0.f, q = 0.f;
        for (int r = r0; r < NV; r += 400 * 4) {
            float v = x[r * 64 + c];
            s += v; q += v * v;
        }
        shA[threadIdx.x] = s; shB[threadIdx.x] = q;
        __syncthreads();
        if (threadIdx.x < 64) {
            s = shA[threadIdx.x] + shA[threadIdx.x + 64] + shA[threadIdx.x + 128] + shA[threadIdx.x + 192];
            q = shB[threadIdx.x] + shB[threadIdx.x + 64] + shB[threadIdx.x + 128] + shB[threadIdx.x + 192];
            atomicAdd(&stats[c], s);
            atomicAdd(&stats[64 + c], q);
        }
    }
}

// ---------------- normalization kernels ----------------

__global__ __launch_bounds__(256) void k_h1(const float* __restrict__ x,
                                            const float* __restrict__ g1,
                                            const float* __restrict__ be1,
                                            const float* __restrict__ stats,
                                            unsigned short* __restrict__ H1) {
    int i = blockIdx.x * 256 + threadIdx.x;   // < NV*16
    if (i >= NV * 16) return;
    int c4 = (i & 15) * 4;
    float4 v = ((const float4*)x)[i];
    float vv[4] = {v.x, v.y, v.z, v.w};
    ushort4 o;
    unsigned short os[4];
#pragma unroll
    for (int j = 0; j < 4; j++) {
        int c = c4 + j;
        float m = stats[c] * (1.0f / NV);
        float var = stats[64 + c] * (1.0f / NV) - m * m;
        float a = g1[c] * rsqrtf(var + EPSV);
        float b = be1[c] - m * a;
        os[j] = f2b(silu_f(vv[j] * a + b));
    }
    o.x = os[0]; o.y = os[1]; o.z = os[2]; o.w = os[3];
    ((ushort4*)H1)[i] = o;
}

__global__ __launch_bounds__(256) void k_h3(unsigned short* __restrict__ H,
                                            const float* __restrict__ g2,
                                            const float* __restrict__ be2,
                                            const float* __restrict__ stats2) {
    int i = blockIdx.x * 256 + threadIdx.x;   // < NV*16 (uint4 of 8 bf16)
    if (i >= NV * 16) return;
    union { uint4 v; unsigned short e[8]; } uu;
    uu.v = ((const uint4*)H)[i];
    int f0 = (i & 15) * 8;
#pragma unroll
    for (int j = 0; j < 8; j++) {
        int f = f0 + j;
        float m = stats2[f] * (1.0f / NV);
        float var = stats2[128 + f] * (1.0f / NV) - m * m;
        float a = g2[f] * rsqrtf(var + EPSV);
        float b = be2[f] - m * a;
        uu.e[j] = f2b(silu_f(b2f(uu.e[j]) * a + b));
    }
    ((uint4*)H)[i] = uu.v;
}

// ---------------- conv kernels ----------------
// V9: block = 256 thr (4 waves), tile 128 rows x 128 cols; wave w owns rows
// [n0 + w*32, +32), all 128 cols (acc[4], 64 AGPR) -> dedup'd A gathers.
// SINGLE-buffered B slab (32KB conv2 / 16KB conv1) + two __syncthreads per k
// -> LDS no longer caps occupancy; __launch_bounds__(256,3) gives 3 blocks/CU
// (12 waves/CU vs 8): per-block barrier-drain bubbles are filled by other blocks.
//   step k: issue A(k+1) gathers + idx(k+2); compute k (ds_read B + MFMA);
//           __syncthreads();           // WAR: all waves done reading B(k); drains gathers
//           stage B(k+1); __syncthreads();   // RAW: stage complete (vmcnt(0) drain)
// All ordering via __syncthreads only — no counted vmcnt anywhere (R3/R6 lesson).

#define C1_STEP(AC, AN, IDXC, IDXN, KK)                                                \
    {                                                                                  \
        if ((KK) + 1 < 27) {                                                           \
            const uint4* pn = (const uint4*)H1 + (long)(IDXC) * 8;                     \
            _Pragma("unroll")                                                          \
            for (int s = 0; s < 4; s++) {                                              \
                AN[s] = make_uint4(0, 0, 0, 0);                                        \
                if ((IDXC) >= 0) AN[s] = pn[s * 2 + h];                                \
            }                                                                          \
        }                                                                              \
        IDXN = ((KK) + 2 < 27 && row0 < NV) ? nbr[((KK) + 2) * NV + row0] : -1;        \
        _Pragma("unroll")                                                              \
        for (int s = 0; s < 4; s++) {                                                  \
            uint4 b0 = sB[(s * 4 + 0) * 64 + lane];                                    \
            uint4 b1v = sB[(s * 4 + 1) * 64 + lane];                                   \
            uint4 b2v = sB[(s * 4 + 2) * 64 + lane];                                   \
            uint4 b3v = sB[(s * 4 + 3) * 64 + lane];                                   \
            acc[0] = MFMA32(bc8(AC[s]), bc8(b0), acc[0]);                              \
            acc[1] = MFMA32(bc8(AC[s]), bc8(b1v), acc[1]);                             \
            acc[2] = MFMA32(bc8(AC[s]), bc8(b2v), acc[2]);                             \
            acc[3] = MFMA32(bc8(AC[s]), bc8(b3v), acc[3]);                             \
        }                                                                              \
        __syncthreads();                                                               \
        if ((KK) + 1 < 27) {                                                           \
            const uint4* gsrc = W1b + ((KK) + 1) * 1024 + (w * 4) * 64 + lane;         \
            _Pragma("unroll")                                                          \
            for (int j = 0; j < 4; j++)                                                \
                gload_lds16(gsrc + j * 64, &sB[(w * 4 + j) * 64]);                     \
        }                                                                              \
        __syncthreads();                                                               \
    }

#define C2_STEP(AC, AN, IDXC, IDXN, KK)                                                \
    {                                                                                  \
        if ((KK) + 1 < 27) {                                                           \
            const uint4* pn = (const uint4*)H3 + (long)(IDXC) * 16;                    \
            _Pragma("unroll")                                                          \
            for (int s = 0; s < 8; s++) {                                              \
                AN[s] = make_uint4(0, 0, 0, 0);                                        \
                if ((IDXC) >= 0) AN[s] = pn[s * 2 + h];                                \
            }                                                                          \
        }                                                                              \
        IDXN = ((KK) + 2 < 27 && row0 < NV) ? nbr[((KK) + 2) * NV + row0] : -1;        \
        _Pragma("unroll")                                                              \
        for (int s = 0; s < 8; s++) {                                                  \
            uint4 b0 = sB[(s * 4 + 0) * 64 + lane];                                    \
            uint4 b1v = sB[(s * 4 + 1) * 64 + lane];                                   \
            uint4 b2v = sB[(s * 4 + 2) * 64 + lane];                                   \
            uint4 b3v = sB[(s * 4 + 3) * 64 + lane];                                   \
            acc[0] = MFMA32(bc8(AC[s]), bc8(b0), acc[0]);                              \
            acc[1] = MFMA32(bc8(AC[s]), bc8(b1v), acc[1]);                             \
            acc[2] = MFMA32(bc8(AC[s]), bc8(b2v), acc[2]);                             \
            acc[3] = MFMA32(bc8(AC[s]), bc8(b3v), acc[3]);                             \
        }                                                                              \
        __syncthreads();                                                               \
        if ((KK) + 1 < 27) {                                                           \
            const uint4* gsrc = W2b + ((KK) + 1) * 2048 + (w * 8) * 64 + lane;         \
            _Pragma("unroll")                                                          \
            for (int j = 0; j < 8; j++)                                                \
                gload_lds16(gsrc + j * 64, &sB[(w * 8 + j) * 64]);                     \
        }                                                                              \
        __syncthreads();                                                               \
    }

#define CD_STEP(AC, AN, IDXC, IDXN, LDSC, LDSN, KK)                                    \
    {                                                                                  \
        if ((KK) + 1 < 8) {                                                            \
            const uint4* pn = (const uint4*)H4 + (long)(IDXC) * 16;                    \
            _Pragma("unroll")                                                          \
            for (int s = 0; s < 8; s++) AN[s] = pn[s * 2 + h];                         \
        }                                                                              \
        IDXN = ((KK) + 2 < 8 && row0 < NDN) ? nbrd[((KK) + 2) * NDN + row0] : 0;       \
        if ((KK) + 1 < 8) {                                                            \
            const uint4* gsrc = Wdb + ((KK) + 1) * 2048 + (w * 8) * 64 + lane;         \
            _Pragma("unroll")                                                          \
            for (int j = 0; j < 8; j++)                                                \
                gload_lds16(gsrc + j * 64, &sB[(LDSN) + (w * 8 + j) * 64]);            \
        }                                                                              \
        _Pragma("unroll")                                                              \
        for (int s = 0; s < 8; s++) {                                                  \
            uint4 b0 = sB[(LDSC) + (s * 4 + 0) * 64 + lane];                           \
            uint4 b1v = sB[(LDSC) + (s * 4 + 1) * 64 + lane];                          \
            uint4 b2v = sB[(LDSC) + (s * 4 + 2) * 64 + lane];                          \
            uint4 b3v = sB[(LDSC) + (s * 4 + 3) * 64 + lane];                          \
            acc[0] = MFMA32(bc8(AC[s]), bc8(b0), acc[0]);                              \
            acc[1] = MFMA32(bc8(AC[s]), bc8(b1v), acc[1]);                             \
            acc[2] = MFMA32(bc8(AC[s]), bc8(b2v), acc[2]);                             \
            acc[3] = MFMA32(bc8(AC[s]), bc8(b3v), acc[3]);                             \
        }                                                                              \
        __syncthreads();                                                               \
    }

__global__ __launch_bounds__(256, 3) void k_conv1(const unsigned short* __restrict__ H1,
                                                  const int* __restrict__ nbr,
                                                  const uint4* __restrict__ W1b,
                                                  const float* __restrict__ b1,
                                                  const int* __restrict__ b_idx,
                                                  const float* __restrict__ tp,
                                                  unsigned short* __restrict__ H2,
                                                  float* __restrict__ stats2) {
    extern __shared__ uint4 sB[];                  // [1024] single-buffered W1 slab (16KB)
    __shared__ float ssum[128], ssq[128];
    int tid = threadIdx.x;
    int w = tid >> 6, lane = tid & 63, m = lane & 31, h = lane >> 5;
    int n0 = blockIdx.x * 128;
    int row0 = n0 + w * 32 + m;
    if (tid < 128) { ssum[tid] = 0.f; ssq[tid] = 0.f; }
    f32x16 z;
#pragma unroll
    for (int r = 0; r < 16; r++) z[r] = 0.f;
    f32x16 acc[4] = {z, z, z, z};
    uint4 aA[4], aB[4];
    int idxE, idxO;

    {   // prologue: idx(0), idx(1); stage B(0); gather A(0)
        int idx0 = (row0 < NV) ? nbr[row0] : -1;
        idxO = (row0 < NV) ? nbr[NV + row0] : -1;
        const uint4* g0 = W1b + (w * 4) * 64 + lane;
#pragma unroll
        for (int j = 0; j < 4; j++) gload_lds16(g0 + j * 64, &sB[(w * 4 + j) * 64]);
        const uint4* p0 = (const uint4*)H1 + (long)idx0 * 8;
#pragma unroll
        for (int s = 0; s < 4; s++) {
            aA[s] = make_uint4(0, 0, 0, 0);
            if (idx0 >= 0) aA[s] = p0[s * 2 + h];
        }
        idxE = idx0;
        __syncthreads();
    }
    for (int k = 0; k < 27; k += 2) {
        C1_STEP(aA, aB, idxO, idxE, k);
        if (k + 1 < 27) C1_STEP(aB, aA, idxE, idxO, (k + 1));
    }

    // epilogue: +b1, time-embed affine, write bf16 h2, accumulate stats2
    int col = m;
    float b1f[4];
#pragma unroll
    for (int nt = 0; nt < 4; nt++) b1f[nt] = b1[nt * 32 + col];
    float sl[4] = {0.f, 0.f, 0.f, 0.f}, ql[4] = {0.f, 0.f, 0.f, 0.f};
#pragma unroll
    for (int r = 0; r < 16; r++) {
        int row = w * 32 + (r & 3) + 8 * (r >> 2) + 4 * h;
        int g = n0 + row;
        if (g < NV) {
            int b = b_idx[g];
            const float* tpb = tp + b * 256;
#pragma unroll
            for (int nt = 0; nt < 4; nt++) {
                int f = nt * 32 + col;
                float val = acc[nt][r] + b1f[nt];
                float h2v = (1.0f + tpb[f]) * val + tpb[128 + f];
                H2[(long)g * 128 + f] = f2b(h2v);
                sl[nt] += h2v; ql[nt] += h2v * h2v;
            }
        }
    }
#pragma unroll
    for (int nt = 0; nt < 4; nt++) {
        int f = nt * 32 + col;
        atomicAdd(&ssum[f], sl[nt]);
        atomicAdd(&ssq[f], ql[nt]);
    }
    __syncthreads();
    if (tid < 128) {
        atomicAdd(&stats2[tid], ssum[tid]);
        atomicAdd(&stats2[128 + tid], ssq[tid]);
    }
}

__global__ __launch_bounds__(256, 3) void k_conv2(const unsigned short* __restrict__ H3,
                                                  const int* __restrict__ nbr,
                                                  const uint4* __restrict__ W2b,
                                                  const float* __restrict__ b2,
                                                  const float* __restrict__ x,
                                                  const uint4* __restrict__ Widb,
                                                  const float* __restrict__ bid,
                                                  unsigned short* __restrict__ H4) {
    extern __shared__ uint4 sB[];                  // [2048] single-buffered W2 slab (32KB)
    int tid = threadIdx.x;
    int w = tid >> 6, lane = tid & 63, m = lane & 31, h = lane >> 5;
    int n0 = blockIdx.x * 128;
    int row0 = n0 + w * 32 + m;
    f32x16 z;
#pragma unroll
    for (int r = 0; r < 16; r++) z[r] = 0.f;
    f32x16 acc[4] = {z, z, z, z};
    uint4 aA[8], aB[8];
    int idxE, idxO;

    {   // prologue
        int idx0 = (row0 < NV) ? nbr[row0] : -1;
        idxO = (row0 < NV) ? nbr[NV + row0] : -1;
        const uint4* g0 = W2b + (w * 8) * 64 + lane;
#pragma unroll
        for (int j = 0; j < 8; j++) gload_lds16(g0 + j * 64, &sB[(w * 8 + j) * 64]);
        const uint4* p0 = (const uint4*)H3 + (long)idx0 * 16;
#pragma unroll
        for (int s = 0; s < 8; s++) {
            aA[s] = make_uint4(0, 0, 0, 0);
            if (idx0 >= 0) aA[s] = p0[s * 2 + h];
        }
        idxE = idx0;
        __syncthreads();
    }
    for (int k = 0; k < 27; k += 2) {
        C2_STEP(aA, aB, idxO, idxE, k);
        if (k + 1 < 27) C2_STEP(aB, aA, idxE, idxO, (k + 1));
    }

    // idconv: x (fp32, CI=64) @ Wid, register-direct (one-time tail, small B)
    {
        uint4 a0[4];
#pragma unroll
        for (int s = 0; s < 4; s++) {
            union { unsigned short e[8]; uint4 v; } u0;
            u0.v = make_uint4(0, 0, 0, 0);
            if (row0 < NV) {
                const float4* xr = (const float4*)(x + (long)row0 * 64);
                float4 f0 = xr[s * 4 + h * 2], f1 = xr[s * 4 + h * 2 + 1];
                u0.e[0] = f2b(f0.x); u0.e[1] = f2b(f0.y); u0.e[2] = f2b(f0.z); u0.e[3] = f2b(f0.w);
                u0.e[4] = f2b(f1.x); u0.e[5] = f2b(f1.y); u0.e[6] = f2b(f1.z); u0.e[7] = f2b(f1.w);
            }
            a0[s] = u0.v;
        }
#pragma unroll
        for (int s = 0; s < 4; s++) {
#pragma unroll
            for (int nt = 0; nt < 4; nt++) {
                uint4 bv = Widb[(s * 4 + nt) * 64 + lane];
                acc[nt] = MFMA32(bc8(a0[s]), bc8(bv), acc[nt]);
            }
        }
    }
    // epilogue: + b2 + bid, write bf16 h4
    int col = m;
#pragma unroll
    for (int nt = 0; nt < 4; nt++) {
        int f = nt * 32 + col;
        float bias = b2[f] + bid[f];
#pragma unroll
        for (int r = 0; r < 16; r++) {
            int row = w * 32 + (r & 3) + 8 * (r >> 2) + 4 * h;
            int g = n0 + row;
            if (g < NV) H4[(long)g * 128 + f] = f2b(acc[nt][r] + bias);
        }
    }
}

__global__ __launch_bounds__(256, 2) void k_down(const unsigned short* __restrict__ H4,
                                                 const int* __restrict__ nbrd,
                                                 const uint4* __restrict__ Wdb,
                                                 float* __restrict__ out) {
    extern __shared__ uint4 sB[];                  // [2][2048] double-buffered Wd slab
    int tid = threadIdx.x;
    int w = tid >> 6, lane = tid & 63, m = lane & 31, h = lane >> 5;
    int n0 = blockIdx.x * 128;
    int row0 = n0 + w * 32 + m;
    f32x16 z;
#pragma unroll
    for (int r = 0; r < 16; r++) z[r] = 0.f;
    f32x16 acc[4] = {z, z, z, z};
    uint4 aA[8], aB[8];
    int idxE, idxO;

    {   // prologue
        int idx0 = (row0 < NDN) ? nbrd[row0] : 0;
        idxO = (row0 < NDN) ? nbrd[NDN + row0] : 0;
        const uint4* g0 = Wdb + (w * 8) * 64 + lane;
#pragma unroll
        for (int j = 0; j < 8; j++) gload_lds16(g0 + j * 64, &sB[(w * 8 + j) * 64]);
        const uint4* p0 = (const uint4*)H4 + (long)idx0 * 16;
#pragma unroll
        for (int s = 0; s < 8; s++) aA[s] = p0[s * 2 + h];
        idxE = idx0;
        __syncthreads();
    }
    for (int k = 0; k < 8; k += 2) {
        CD_STEP(aA, aB, idxO, idxE, 0, 2048, k);
        CD_STEP(aB, aA, idxE, idxO, 2048, 0, (k + 1));
    }

    int col = m;
#pragma unroll
    for (int nt = 0; nt < 4; nt++) {
        int f = nt * 32 + col;
#pragma unroll
        for (int r = 0; r < 16; r++) {
            int row = w * 32 + (r & 3) + 8 * (r >> 2) + 4 * h;
            int g = n0 + row;
            if (g < NDN) out[(long)g * 128 + f] = acc[nt][r];
        }
    }
}

// ---------------- launch ----------------

extern "C" void kernel_launch(void* const* d_in, const int* in_sizes, int n_in,
                              void* d_out, int out_size, void* d_ws, size_t ws_size,
                              hipStream_t stream) {
    const float* x   = (const float*)d_in[0];
    const float* t   = (const float*)d_in[1];
    const int* b_idx = (const int*)d_in[2];
    const int* nbr   = (const int*)d_in[3];
    const int* nbrd  = (const int*)d_in[4];
    const float* g1  = (const float*)d_in[5];
    const float* be1 = (const float*)d_in[6];
    const float* W1  = (const float*)d_in[7];
    const float* b1  = (const float*)d_in[8];
    const float* Wt  = (const float*)d_in[9];
    const float* bt  = (const float*)d_in[10];
    const float* g2  = (const float*)d_in[11];
    const float* be2 = (const float*)d_in[12];
    const float* W2  = (const float*)d_in[13];
    const float* b2  = (const float*)d_in[14];
    const float* Wid = (const float*)d_in[15];
    const float* bid = (const float*)d_in[16];
    const float* Wd  = (const float*)d_in[17];
    float* out = (float*)d_out;

    char* ws = (char*)d_ws;
    float* stats1 = (float*)(ws + OFF_STATS1);
    float* stats2 = (float*)(ws + OFF_STATS2);
    float* tp     = (float*)(ws + OFF_TP);
    uint4* W1b    = (uint4*)(ws + OFF_W1B);
    uint4* W2b    = (uint4*)(ws + OFF_W2B);
    uint4* Wdb    = (uint4*)(ws + OFF_WDB);
    uint4* Widb   = (uint4*)(ws + OFF_WIDB);
    unsigned short* H1 = (unsigned short*)(ws + OFF_H1);
    unsigned short* H2 = (unsigned short*)(ws + OFF_H2);
    unsigned short* H4 = (unsigned short*)(ws + OFF_H4);

    hipMemsetAsync(ws, 0, 4096, stream);   // zero stats1 + stats2
    k_pre<<<808, 256, 0, stream>>>(x, t, Wt, bt, W1, W2, Wd, Wid,
                                   stats1, tp, W1b, W2b, Wdb, Widb);
    k_h1<<<12500, 256, 0, stream>>>(x, g1, be1, stats1, H1);
    k_conv1<<<(NV + 127) / 128, 256, 1024 * 16, stream>>>(H1, nbr, W1b, b1, b_idx, tp, H2, stats2);
    k_h3<<<12500, 256, 0, stream>>>(H2, g2, be2, stats2);
    k_conv2<<<(NV + 127) / 128, 256, 2048 * 16, stream>>>(H2, nbr, W2b, b2, x, Widb, bid, H4);
    k_down<<<(NDN + 127) / 128, 256, 2 * 2048 * 16, stream>>>(H4, nbrd, Wdb, out);
}

// Round 10
// 639.775 us; speedup vs baseline: 1.0459x; 1.0459x over previous
//
#include <hip/hip_runtime.h>

#define NV 200000
#define NDN 25000
#define EPSV 1e-5f

typedef short bf16x8 __attribute__((ext_vector_type(8)));
typedef float f32x16 __attribute__((ext_vector_type(16)));

static __device__ __forceinline__ float silu_f(float v) { return v / (1.0f + __expf(-v)); }
static __device__ __forceinline__ unsigned short f2b(float f) {
    unsigned u = __float_as_uint(f);
    return (unsigned short)((u + 0x7FFFu + ((u >> 16) & 1u)) >> 16);
}
static __device__ __forceinline__ float b2f(unsigned short h) {
    return __uint_as_float(((unsigned)h) << 16);
}
static __device__ __forceinline__ bf16x8 bc8(uint4 v) { return __builtin_bit_cast(bf16x8, v); }
#define MFMA32(a, b, c) __builtin_amdgcn_mfma_f32_32x32x16_bf16(a, b, c, 0, 0, 0)

// async global->LDS, 16B per lane; dest = wave-uniform base + lane*16
static __device__ __forceinline__ void gload_lds16(const uint4* g, uint4* l) {
    __builtin_amdgcn_global_load_lds((const __attribute__((address_space(1))) unsigned*)(g),
                                     (__attribute__((address_space(3))) unsigned*)(l), 16, 0, 0);
}

// workspace byte offsets
#define OFF_STATS1 0                               // 128 f32 (sum[64], sumsq[64])
#define OFF_STATS2 512                             // 256 f32
#define OFF_TP     4096                            // 16*256 f32
#define OFF_W1B    32768                           // bf16 swizzled 27*64*128
#define OFF_W2B    (OFF_W1B + 27 * 64 * 128 * 2)   // 27*128*128
#define OFF_WDB    (OFF_W2B + 27 * 128 * 128 * 2)  // 8*128*128
#define OFF_WIDB   (OFF_WDB + 8 * 128 * 128 * 2)   // 64*128
#define OFF_H1     (2u << 20)                      // bf16 NV*64
#define OFF_H2     (28u << 20)                     // bf16 NV*128 (h2 then h3 in place)
#define OFF_H4     (80u << 20)                     // bf16 NV*128

// ---------------- fused preprocessing kernel ----------------
// blocks [0,108): swz W1 | [108,324): swz W2 | [324,388): swz Wd | [388,392): swz Wid
// blocks [392,408): tp   | [408,808): stats1 (fixed stride 400)

static __device__ __forceinline__ void swz_role(const float* __restrict__ W, uint4* __restrict__ dst,
                                                int Kc, int S, int blk) {
    int t = blk * 256 + threadIdx.x;
    int total = Kc * S * 4 * 64;
    if (t >= total) return;
    int L = t & 63;
    int u = t >> 6;
    int nt = u & 3; u >>= 2;
    int s = u % S;
    int kk = u / S;
    int CI = S * 16;
    int c0 = s * 16 + (L >> 5) * 8;
    int f = nt * 32 + (L & 31);
    union { unsigned short e[8]; uint4 v; } uu;
#pragma unroll
    for (int j = 0; j < 8; j++) uu.e[j] = f2b(W[(kk * CI + c0 + j) * 128 + f]);
    dst[t] = uu.v;
}

__global__ __launch_bounds__(256) void k_pre(const float* __restrict__ x,
                                             const float* __restrict__ t,
                                             const float* __restrict__ Wt,
                                             const float* __restrict__ bt,
                                             const float* __restrict__ W1,
                                             const float* __restrict__ W2,
                                             const float* __restrict__ Wd,
                                             const float* __restrict__ Wid,
                                             float* __restrict__ stats,
                                             float* __restrict__ tp,
                                             uint4* __restrict__ W1b,
                                             uint4* __restrict__ W2b,
                                             uint4* __restrict__ Wdb,
                                             uint4* __restrict__ Widb) {
    __shared__ float shA[256], shB[256];
    int b = blockIdx.x;
    if (b < 108) {
        swz_role(W1, W1b, 27, 4, b);
    } else if (b < 324) {
        swz_role(W2, W2b, 27, 8, b - 108);
    } else if (b < 388) {
        swz_role(Wd, Wdb, 8, 8, b - 324);
    } else if (b < 392) {
        swz_role(Wid, Widb, 1, 4, b - 388);
    } else if (b < 408) {
        int bb = b - 392, o = threadIdx.x;
        shA[o] = silu_f(t[bb * 256 + o]);
        __syncthreads();
        float acc = bt[o];
        for (int e = 0; e < 256; e++) acc += shA[e] * Wt[e * 256 + o];
        tp[bb * 256 + o] = acc;
    } else {
        int bb = b - 408;                        // 400 stats1 blocks, FIXED stride
        int c = threadIdx.x & 63;
        int r0 = bb * 4 + (threadIdx.x >> 6);
        float s = 0.f, q = 0.f;
        for (int r = r0; r < NV; r += 400 * 4) {
            float v = x[r * 64 + c];
            s += v; q += v * v;
        }
        shA[threadIdx.x] = s; shB[threadIdx.x] = q;
        __syncthreads();
        if (threadIdx.x < 64) {
            s = shA[threadIdx.x] + shA[threadIdx.x + 64] + shA[threadIdx.x + 128] + shA[threadIdx.x + 192];
            q = shB[threadIdx.x] + shB[threadIdx.x + 64] + shB[threadIdx.x + 128] + shB[threadIdx.x + 192];
            atomicAdd(&stats[c], s);
            atomicAdd(&stats[64 + c], q);
        }
    }
}

// ---------------- normalization kernels ----------------

__global__ __launch_bounds__(256) void k_h1(const float* __restrict__ x,
                                            const float* __restrict__ g1,
                                            const float* __restrict__ be1,
                                            const float* __restrict__ stats,
                                            unsigned short* __restrict__ H1) {
    int i = blockIdx.x * 256 + threadIdx.x;   // < NV*16
    if (i >= NV * 16) return;
    int c4 = (i & 15) * 4;
    float4 v = ((const float4*)x)[i];
    float vv[4] = {v.x, v.y, v.z, v.w};
    ushort4 o;
    unsigned short os[4];
#pragma unroll
    for (int j = 0; j < 4; j++) {
        int c = c4 + j;
        float m = stats[c] * (1.0f / NV);
        float var = stats[64 + c] * (1.0f / NV) - m * m;
        float a = g1[c] * rsqrtf(var + EPSV);
        float b = be1[c] - m * a;
        os[j] = f2b(silu_f(vv[j] * a + b));
    }
    o.x = os[0]; o.y = os[1]; o.z = os[2]; o.w = os[3];
    ((ushort4*)H1)[i] = o;
}

__global__ __launch_bounds__(256) void k_h3(unsigned short* __restrict__ H,
                                            const float* __restrict__ g2,
                                            const float* __restrict__ be2,
                                            const float* __restrict__ stats2) {
    int i = blockIdx.x * 256 + threadIdx.x;   // < NV*16 (uint4 of 8 bf16)
    if (i >= NV * 16) return;
    union { uint4 v; unsigned short e[8]; } uu;
    uu.v = ((const uint4*)H)[i];
    int f0 = (i & 15) * 8;
#pragma unroll
    for (int j = 0; j < 8; j++) {
        int f = f0 + j;
        float m = stats2[f] * (1.0f / NV);
        float var = stats2[128 + f] * (1.0f / NV) - m * m;
        float a = g2[f] * rsqrtf(var + EPSV);
        float b = be2[f] - m * a;
        uu.e[j] = f2b(silu_f(b2f(uu.e[j]) * a + b));
    }
    ((uint4*)H)[i] = uu.v;
}

// ---------------- conv kernels ----------------
// conv1: R8-proven (double-buffered B slab 32KB, ONE __syncthreads/k, (256,2)) —
//        its LDS already permits 3 blocks/CU; overlapped stage beats serialized (R9 A/B).
// conv2: R9-proven (single-buffered B slab 32KB, TWO __syncthreads/k, (256,3)) —
//        LDS halving raised occupancy 18->27%, 275->257us (R9 A/B).
// Both: wave w owns rows [n0+w*32,+32), all 128 cols (acc[4], 64 AGPR), dedup'd A gathers;
// all ordering via __syncthreads only (vmcnt(0)-draining) — no counted waits (R3/R6 lesson).

#define C1_STEP(AC, AN, IDXC, IDXN, LDSC, LDSN, KK)                                    \
    {                                                                                  \
        if ((KK) + 1 < 27) {                                                           \
            const uint4* pn = (const uint4*)H1 + (long)(IDXC) * 8;                     \
            _Pragma("unroll")                                                          \
            for (int s = 0; s < 4; s++) {                                              \
                AN[s] = make_uint4(0, 0, 0, 0);                                        \
                if ((IDXC) >= 0) AN[s] = pn[s * 2 + h];                                \
            }                                                                          \
        }                                                                              \
        IDXN = ((KK) + 2 < 27 && row0 < NV) ? nbr[((KK) + 2) * NV + row0] : -1;        \
        if ((KK) + 1 < 27) {                                                           \
            const uint4* gsrc = W1b + ((KK) + 1) * 1024 + (w * 4) * 64 + lane;         \
            _Pragma("unroll")                                                          \
            for (int j = 0; j < 4; j++)                                                \
                gload_lds16(gsrc + j * 64, &sB[(LDSN) + (w * 4 + j) * 64]);            \
        }                                                                              \
        _Pragma("unroll")                                                              \
        for (int s = 0; s < 4; s++) {                                                  \
            uint4 b0 = sB[(LDSC) + (s * 4 + 0) * 64 + lane];                           \
            uint4 b1v = sB[(LDSC) + (s * 4 + 1) * 64 + lane];                          \
            uint4 b2v = sB[(LDSC) + (s * 4 + 2) * 64 + lane];                          \
            uint4 b3v = sB[(LDSC) + (s * 4 + 3) * 64 + lane];                          \
            acc[0] = MFMA32(bc8(AC[s]), bc8(b0), acc[0]);                              \
            acc[1] = MFMA32(bc8(AC[s]), bc8(b1v), acc[1]);                             \
            acc[2] = MFMA32(bc8(AC[s]), bc8(b2v), acc[2]);                             \
            acc[3] = MFMA32(bc8(AC[s]), bc8(b3v), acc[3]);                             \
        }                                                                              \
        __syncthreads();                                                               \
    }

#define C2_STEP(AC, AN, IDXC, IDXN, KK)                                                \
    {                                                                                  \
        if ((KK) + 1 < 27) {                                                           \
            const uint4* pn = (const uint4*)H3 + (long)(IDXC) * 16;                    \
            _Pragma("unroll")                                                          \
            for (int s = 0; s < 8; s++) {                                              \
                AN[s] = make_uint4(0, 0, 0, 0);                                        \
                if ((IDXC) >= 0) AN[s] = pn[s * 2 + h];                                \
            }                                                                          \
        }                                                                              \
        IDXN = ((KK) + 2 < 27 && row0 < NV) ? nbr[((KK) + 2) * NV + row0] : -1;        \
        _Pragma("unroll")                                                              \
        for (int s = 0; s < 8; s++) {                                                  \
            uint4 b0 = sB[(s * 4 + 0) * 64 + lane];                                    \
            uint4 b1v = sB[(s * 4 + 1) * 64 + lane];                                   \
            uint4 b2v = sB[(s * 4 + 2) * 64 + lane];                                   \
            uint4 b3v = sB[(s * 4 + 3) * 64 + lane];                                   \
            acc[0] = MFMA32(bc8(AC[s]), bc8(b0), acc[0]);                              \
            acc[1] = MFMA32(bc8(AC[s]), bc8(b1v), acc[1]);                             \
            acc[2] = MFMA32(bc8(AC[s]), bc8(b2v), acc[2]);                             \
            acc[3] = MFMA32(bc8(AC[s]), bc8(b3v), acc[3]);                             \
        }                                                                              \
        __syncthreads();                                                               \
        if ((KK) + 1 < 27) {                                                           \
            const uint4* gsrc = W2b + ((KK) + 1) * 2048 + (w * 8) * 64 + lane;         \
            _Pragma("unroll")                                                          \
            for (int j = 0; j < 8; j++)                                                \
                gload_lds16(gsrc + j * 64, &sB[(w * 8 + j) * 64]);                     \
        }                                                                              \
        __syncthreads();                                                               \
    }

#define CD_STEP(AC, AN, IDXC, IDXN, LDSC, LDSN, KK)                                    \
    {                                                                                  \
        if ((KK) + 1 < 8) {                                                            \
            const uint4* pn = (const uint4*)H4 + (long)(IDXC) * 16;                    \
            _Pragma("unroll")                                                          \
            for (int s = 0; s < 8; s++) AN[s] = pn[s * 2 + h];                         \
        }                                                                              \
        IDXN = ((KK) + 2 < 8 && row0 < NDN) ? nbrd[((KK) + 2) * NDN + row0] : 0;       \
        if ((KK) + 1 < 8) {                                                            \
            const uint4* gsrc = Wdb + ((KK) + 1) * 2048 + (w * 8) * 64 + lane;         \
            _Pragma("unroll")                                                          \
            for (int j = 0; j < 8; j++)                                                \
                gload_lds16(gsrc + j * 64, &sB[(LDSN) + (w * 8 + j) * 64]);            \
        }                                                                              \
        _Pragma("unroll")                                                              \
        for (int s = 0; s < 8; s++) {                                                  \
            uint4 b0 = sB[(LDSC) + (s * 4 + 0) * 64 + lane];                           \
            uint4 b1v = sB[(LDSC) + (s * 4 + 1) * 64 + lane];                          \
            uint4 b2v = sB[(LDSC) + (s * 4 + 2) * 64 + lane];                          \
            uint4 b3v = sB[(LDSC) + (s * 4 + 3) * 64 + lane];                          \
            acc[0] = MFMA32(bc8(AC[s]), bc8(b0), acc[0]);                              \
            acc[1] = MFMA32(bc8(AC[s]), bc8(b1v), acc[1]);                             \
            acc[2] = MFMA32(bc8(AC[s]), bc8(b2v), acc[2]);                             \
            acc[3] = MFMA32(bc8(AC[s]), bc8(b3v), acc[3]);                             \
        }                                                                              \
        __syncthreads();                                                               \
    }

__global__ __launch_bounds__(256, 2) void k_conv1(const unsigned short* __restrict__ H1,
                                                  const int* __restrict__ nbr,
                                                  const uint4* __restrict__ W1b,
                                                  const float* __restrict__ b1,
                                                  const int* __restrict__ b_idx,
                                                  const float* __restrict__ tp,
                                                  unsigned short* __restrict__ H2,
                                                  float* __restrict__ stats2) {
    extern __shared__ uint4 sB[];                  // [2][1024] double-buffered W1 slab
    __shared__ float ssum[128], ssq[128];
    int tid = threadIdx.x;
    int w = tid >> 6, lane = tid & 63, m = lane & 31, h = lane >> 5;
    int n0 = blockIdx.x * 128;
    int row0 = n0 + w * 32 + m;
    if (tid < 128) { ssum[tid] = 0.f; ssq[tid] = 0.f; }
    f32x16 z;
#pragma unroll
    for (int r = 0; r < 16; r++) z[r] = 0.f;
    f32x16 acc[4] = {z, z, z, z};
    uint4 aA[4], aB[4];
    int idxE, idxO;

    {   // prologue: idx(0), idx(1); stage B(0); gather A(0)
        int idx0 = (row0 < NV) ? nbr[row0] : -1;
        idxO = (row0 < NV) ? nbr[NV + row0] : -1;
        const uint4* g0 = W1b + (w * 4) * 64 + lane;
#pragma unroll
        for (int j = 0; j < 4; j++) gload_lds16(g0 + j * 64, &sB[(w * 4 + j) * 64]);
        const uint4* p0 = (const uint4*)H1 + (long)idx0 * 8;
#pragma unroll
        for (int s = 0; s < 4; s++) {
            aA[s] = make_uint4(0, 0, 0, 0);
            if (idx0 >= 0) aA[s] = p0[s * 2 + h];
        }
        idxE = idx0;
        __syncthreads();
    }
    for (int k = 0; k < 27; k += 2) {
        C1_STEP(aA, aB, idxO, idxE, 0, 1024, k);
        if (k + 1 < 27) C1_STEP(aB, aA, idxE, idxO, 1024, 0, (k + 1));
    }

    // epilogue: +b1, time-embed affine, write bf16 h2, accumulate stats2
    int col = m;
    float b1f[4];
#pragma unroll
    for (int nt = 0; nt < 4; nt++) b1f[nt] = b1[nt * 32 + col];
    float sl[4] = {0.f, 0.f, 0.f, 0.f}, ql[4] = {0.f, 0.f, 0.f, 0.f};
#pragma unroll
    for (int r = 0; r < 16; r++) {
        int row = w * 32 + (r & 3) + 8 * (r >> 2) + 4 * h;
        int g = n0 + row;
        if (g < NV) {
            int b = b_idx[g];
            const float* tpb = tp + b * 256;
#pragma unroll
            for (int nt = 0; nt < 4; nt++) {
                int f = nt * 32 + col;
                float val = acc[nt][r] + b1f[nt];
                float h2v = (1.0f + tpb[f]) * val + tpb[128 + f];
                H2[(long)g * 128 + f] = f2b(h2v);
                sl[nt] += h2v; ql[nt] += h2v * h2v;
            }
        }
    }
#pragma unroll
    for (int nt = 0; nt < 4; nt++) {
        int f = nt * 32 + col;
        atomicAdd(&ssum[f], sl[nt]);
        atomicAdd(&ssq[f], ql[nt]);
    }
    __syncthreads();
    if (tid < 128) {
        atomicAdd(&stats2[tid], ssum[tid]);
        atomicAdd(&stats2[128 + tid], ssq[tid]);
    }
}

__global__ __launch_bounds__(256, 3) void k_conv2(const unsigned short* __restrict__ H3,
                                                  const int* __restrict__ nbr,
                                                  const uint4* __restrict__ W2b,
                                                  const float* __restrict__ b2,
                                                  const float* __restrict__ x,
                                                  const uint4* __restrict__ Widb,
                                                  const float* __restrict__ bid,
                                                  unsigned short* __restrict__ H4) {
    extern __shared__ uint4 sB[];                  // [2048] single-buffered W2 slab (32KB)
    int tid = threadIdx.x;
    int w = tid >> 6, lane = tid & 63, m = lane & 31, h = lane >> 5;
    int n0 = blockIdx.x * 128;
    int row0 = n0 + w * 32 + m;
    f32x16 z;
#pragma unroll
    for (int r = 0; r < 16; r++) z[r] = 0.f;
    f32x16 acc[4] = {z, z, z, z};
    uint4 aA[8], aB[8];
    int idxE, idxO;

    {   // prologue
        int idx0 = (row0 < NV) ? nbr[row0] : -1;
        idxO = (row0 < NV) ? nbr[NV + row0] : -1;
        const uint4* g0 = W2b + (w * 8) * 64 + lane;
#pragma unroll
        for (int j = 0; j < 8; j++) gload_lds16(g0 + j * 64, &sB[(w * 8 + j) * 64]);
        const uint4* p0 = (const uint4*)H3 + (long)idx0 * 16;
#pragma unroll
        for (int s = 0; s < 8; s++) {
            aA[s] = make_uint4(0, 0, 0, 0);
            if (idx0 >= 0) aA[s] = p0[s * 2 + h];
        }
        idxE = idx0;
        __syncthreads();
    }
    for (int k = 0; k < 27; k += 2) {
        C2_STEP(aA, aB, idxO, idxE, k);
        if (k + 1 < 27) C2_STEP(aB, aA, idxE, idxO, (k + 1));
    }

    // idconv: x (fp32, CI=64) @ Wid, register-direct (one-time tail, small B)
    {
        uint4 a0[4];
#pragma unroll
        for (int s = 0; s < 4; s++) {
            union { unsigned short e[8]; uint4 v; } u0;
            u0.v = make_uint4(0, 0, 0, 0);
            if (row0 < NV) {
                const float4* xr = (const float4*)(x + (long)row0 * 64);
                float4 f0 = xr[s * 4 + h * 2], f1 = xr[s * 4 + h * 2 + 1];
                u0.e[0] = f2b(f0.x); u0.e[1] = f2b(f0.y); u0.e[2] = f2b(f0.z); u0.e[3] = f2b(f0.w);
                u0.e[4] = f2b(f1.x); u0.e[5] = f2b(f1.y); u0.e[6] = f2b(f1.z); u0.e[7] = f2b(f1.w);
            }
            a0[s] = u0.v;
        }
#pragma unroll
        for (int s = 0; s < 4; s++) {
#pragma unroll
            for (int nt = 0; nt < 4; nt++) {
                uint4 bv = Widb[(s * 4 + nt) * 64 + lane];
                acc[nt] = MFMA32(bc8(a0[s]), bc8(bv), acc[nt]);
            }
        }
    }
    // epilogue: + b2 + bid, write bf16 h4
    int col = m;
#pragma unroll
    for (int nt = 0; nt < 4; nt++) {
        int f = nt * 32 + col;
        float bias = b2[f] + bid[f];
#pragma unroll
        for (int r = 0; r < 16; r++) {
            int row = w * 32 + (r & 3) + 8 * (r >> 2) + 4 * h;
            int g = n0 + row;
            if (g < NV) H4[(long)g * 128 + f] = f2b(acc[nt][r] + bias);
        }
    }
}

__global__ __launch_bounds__(256, 2) void k_down(const unsigned short* __restrict__ H4,
                                                 const int* __restrict__ nbrd,
                                                 const uint4* __restrict__ Wdb,
                                                 float* __restrict__ out) {
    extern __shared__ uint4 sB[];                  // [2][2048] double-buffered Wd slab
    int tid = threadIdx.x;
    int w = tid >> 6, lane = tid & 63, m = lane & 31, h = lane >> 5;
    int n0 = blockIdx.x * 128;
    int row0 = n0 + w * 32 + m;
    f32x16 z;
#pragma unroll
    for (int r = 0; r < 16; r++) z[r] = 0.f;
    f32x16 acc[4] = {z, z, z, z};
    uint4 aA[8], aB[8];
    int idxE, idxO;

    {   // prologue
        int idx0 = (row0 < NDN) ? nbrd[row0] : 0;
        idxO = (row0 < NDN) ? nbrd[NDN + row0] : 0;
        const uint4* g0 = Wdb + (w * 8) * 64 + lane;
#pragma unroll
        for (int j = 0; j < 8; j++) gload_lds16(g0 + j * 64, &sB[(w * 8 + j) * 64]);
        const uint4* p0 = (const uint4*)H4 + (long)idx0 * 16;
#pragma unroll
        for (int s = 0; s < 8; s++) aA[s] = p0[s * 2 + h];
        idxE = idx0;
        __syncthreads();
    }
    for (int k = 0; k < 8; k += 2) {
        CD_STEP(aA, aB, idxO, idxE, 0, 2048, k);
        CD_STEP(aB, aA, idxE, idxO, 2048, 0, (k + 1));
    }

    int col = m;
#pragma unroll
    for (int nt = 0; nt < 4; nt++) {
        int f = nt * 32 + col;
#pragma unroll
        for (int r = 0; r < 16; r++) {
            int row = w * 32 + (r & 3) + 8 * (r >> 2) + 4 * h;
            int g = n0 + row;
            if (g < NDN) out[(long)g * 128 + f] = acc[nt][r];
        }
    }
}

// ---------------- launch ----------------

extern "C" void kernel_launch(void* const* d_in, const int* in_sizes, int n_in,
                              void* d_out, int out_size, void* d_ws, size_t ws_size,
                              hipStream_t stream) {
    const float* x   = (const float*)d_in[0];
    const float* t   = (const float*)d_in[1];
    const int* b_idx = (const int*)d_in[2];
    const int* nbr   = (const int*)d_in[3];
    const int* nbrd  = (const int*)d_in[4];
    const float* g1  = (const float*)d_in[5];
    const float* be1 = (const float*)d_in[6];
    const float* W1  = (const float*)d_in[7];
    const float* b1  = (const float*)d_in[8];
    const float* Wt  = (const float*)d_in[9];
    const float* bt  = (const float*)d_in[10];
    const float* g2  = (const float*)d_in[11];
    const float* be2 = (const float*)d_in[12];
    const float* W2  = (const float*)d_in[13];
    const float* b2  = (const float*)d_in[14];
    const float* Wid = (const float*)d_in[15];
    const float* bid = (const float*)d_in[16];
    const float* Wd  = (const float*)d_in[17];
    float* out = (float*)d_out;

    char* ws = (char*)d_ws;
    float* stats1 = (float*)(ws + OFF_STATS1);
    float* stats2 = (float*)(ws + OFF_STATS2);
    float* tp     = (float*)(ws + OFF_TP);
    uint4* W1b    = (uint4*)(ws + OFF_W1B);
    uint4* W2b    = (uint4*)(ws + OFF_W2B);
    uint4* Wdb    = (uint4*)(ws + OFF_WDB);
    uint4* Widb   = (uint4*)(ws + OFF_WIDB);
    unsigned short* H1 = (unsigned short*)(ws + OFF_H1);
    unsigned short* H2 = (unsigned short*)(ws + OFF_H2);
    unsigned short* H4 = (unsigned short*)(ws + OFF_H4);

    hipMemsetAsync(ws, 0, 4096, stream);   // zero stats1 + stats2
    k_pre<<<808, 256, 0, stream>>>(x, t, Wt, bt, W1, W2, Wd, Wid,
                                   stats1, tp, W1b, W2b, Wdb, Widb);
    k_h1<<<12500, 256, 0, stream>>>(x, g1, be1, stats1, H1);
    k_conv1<<<(NV + 127) / 128, 256, 2 * 1024 * 16, stream>>>(H1, nbr, W1b, b1, b_idx, tp, H2, stats2);
    k_h3<<<12500, 256, 0, stream>>>(H2, g2, be2, stats2);
    k_conv2<<<(NV + 127) / 128, 256, 2048 * 16, stream>>>(H2, nbr, W2b, b2, x, Widb, bid, H4);
    k_down<<<(NDN + 127) / 128, 256, 2 * 2048 * 16, stream>>>(H4, nbrd, Wdb, out);
}